// Round 1
// baseline (872.636 us; speedup 1.0000x reference)
//
#include <hip/hip_runtime.h>
#include <cmath>

#define NGRID 128
#define FEAT 16
#define WIDTH 64
#define NPTS 262144
#define IN_MLP 25

__device__ __forceinline__ void fma4(float4& a, float w, const float4 c) {
    a.x = fmaf(w, c.x, a.x);
    a.y = fmaf(w, c.y, a.y);
    a.z = fmaf(w, c.z, a.z);
    a.w = fmaf(w, c.w, a.w);
}

__global__ __launch_bounds__(256) void gridnet_kernel(
    const float* __restrict__ x,
    const float* __restrict__ grid,
    const float* __restrict__ w1,
    const float* __restrict__ b1,
    const float* __restrict__ w2,
    const float* __restrict__ b2,
    float* __restrict__ out)
{
    const int p = blockIdx.x * blockDim.x + threadIdx.x;
    if (p >= NPTS) return;

    // ---- per-dimension index + cubic weight setup ----
    int   idx[3][4];
    float wgt[3][4];
    float t[3];
    #pragma unroll
    for (int d = 0; d < 3; ++d) {
        const float u  = x[3 * p + d] * 127.0f;   // x * (n - 1)
        const float fu = floorf(u);
        const float td = u - fu;
        t[d] = td;
        const int i0 = (int)fu;
        #pragma unroll
        for (int o = 0; o < 4; ++o) {
            int v = i0 - 1 + o;
            v = v < 0 ? 0 : (v > 127 ? 127 : v);
            idx[d][o] = v;
        }
        const float t2 = td * td;
        const float t3 = t2 * td;
        wgt[d][0] = 0.5f * (-t3 + 2.0f * t2 - td);
        wgt[d][1] = 0.5f * (3.0f * t3 - 5.0f * t2 + 2.0f);
        wgt[d][2] = 0.5f * (-3.0f * t3 + 4.0f * t2 + td);
        wgt[d][3] = 0.5f * (t3 - t2);
    }

    // ---- tricubic gather: 64 cells x 16 feats (4x float4 per cell) ----
    float4 acc0 = make_float4(0.f, 0.f, 0.f, 0.f);
    float4 acc1 = acc0, acc2 = acc0, acc3 = acc0;
    const float4* __restrict__ g4 = (const float4*)grid;

    #pragma unroll
    for (int a = 0; a < 4; ++a) {
        const int   xo = idx[0][a] * NGRID;
        const float wa = wgt[0][a];
        #pragma unroll
        for (int b = 0; b < 4; ++b) {
            const int   xyo = (xo + idx[1][b]) * NGRID;
            const float wab = wa * wgt[1][b];
            #pragma unroll
            for (int c = 0; c < 4; ++c) {
                const float w = wab * wgt[2][c];
                const float4* cell = g4 + (size_t)(xyo + idx[2][c]) * 4;
                const float4 c0 = cell[0];
                const float4 c1 = cell[1];
                const float4 c2 = cell[2];
                const float4 c3 = cell[3];
                fma4(acc0, w, c0);
                fma4(acc1, w, c1);
                fma4(acc2, w, c2);
                fma4(acc3, w, c3);
            }
        }
    }

    // ---- assemble MLP input: 16 feats + 9 positional sins ----
    float h[IN_MLP];
    h[0]  = acc0.x; h[1]  = acc0.y; h[2]  = acc0.z; h[3]  = acc0.w;
    h[4]  = acc1.x; h[5]  = acc1.y; h[6]  = acc1.z; h[7]  = acc1.w;
    h[8]  = acc2.x; h[9]  = acc2.y; h[10] = acc2.z; h[11] = acc2.w;
    h[12] = acc3.x; h[13] = acc3.y; h[14] = acc3.z; h[15] = acc3.w;

    const float TWO_PI = 6.28318530717958647692f;
    #pragma unroll
    for (int k = 0; k < 3; ++k) {
        #pragma unroll
        for (int d = 0; d < 3; ++d) {
            h[16 + k * 3 + d] = sinf(TWO_PI * (float)(k + 1) * t[d]);
        }
    }

    // ---- MLP: 25 -> 64 (swish) -> 1 ----
    // Weight reads are wave-uniform addresses -> compiler scalarizes to s_load.
    float o = b2[0];
    #pragma unroll 4
    for (int j = 0; j < WIDTH; ++j) {
        float hj = b1[j];
        #pragma unroll
        for (int k = 0; k < IN_MLP; ++k) {
            hj = fmaf(h[k], w1[j * IN_MLP + k], hj);
        }
        const float sig = 1.0f / (1.0f + expf(-hj));
        o = fmaf(hj * sig, w2[j], o);
    }
    out[p] = o;
}

extern "C" void kernel_launch(void* const* d_in, const int* in_sizes, int n_in,
                              void* d_out, int out_size, void* d_ws, size_t ws_size,
                              hipStream_t stream) {
    const float* x    = (const float*)d_in[0];
    const float* grid = (const float*)d_in[1];
    const float* w1   = (const float*)d_in[2];
    const float* b1   = (const float*)d_in[3];
    const float* w2   = (const float*)d_in[4];
    const float* b2   = (const float*)d_in[5];
    float* out = (float*)d_out;

    const int threads = 256;
    const int blocks  = (NPTS + threads - 1) / threads;
    gridnet_kernel<<<blocks, threads, 0, stream>>>(x, grid, w1, b1, w2, b2, out);
}

// Round 6
// 689.949 us; speedup vs baseline: 1.2648x; 1.2648x over previous
//
#include <hip/hip_runtime.h>
#include <cmath>

#define NGRID 128
#define FEAT 16
#define WIDTH 64
#define NPTS 262144
#define IN_MLP 25

__device__ __forceinline__ void fma4(float4& a, float w, const float4 c) {
    a.x = fmaf(w, c.x, a.x);
    a.y = fmaf(w, c.y, a.y);
    a.z = fmaf(w, c.z, a.z);
    a.w = fmaf(w, c.w, a.w);
}

__global__ __launch_bounds__(256, 4) void gridnet_kernel(
    const float* __restrict__ x,
    const float* __restrict__ grid,
    const float* __restrict__ w1,
    const float* __restrict__ b1,
    const float* __restrict__ w2,
    const float* __restrict__ b2,
    float* __restrict__ out)
{
    const int p = blockIdx.x * blockDim.x + threadIdx.x;
    if (p >= NPTS) return;

    // ---- per-dimension index + cubic weight setup ----
    // Offsets precomputed in float4 units: cell4 = ((ix*128+iy)*128+iz)*4
    int   offa[4], offb[4], offc[4];
    float wx[4], wy[4], wz[4];
    float t[3];
    #pragma unroll
    for (int d = 0; d < 3; ++d) {
        const float u  = x[3 * p + d] * 127.0f;   // x * (n - 1)
        const float fu = floorf(u);
        const float td = u - fu;
        t[d] = td;
        const int i0 = (int)fu;
        const float t2 = td * td;
        const float t3 = t2 * td;
        float w0 = 0.5f * (-t3 + 2.0f * t2 - td);
        float w1v = 0.5f * (3.0f * t3 - 5.0f * t2 + 2.0f);
        float w2v = 0.5f * (-3.0f * t3 + 4.0f * t2 + td);
        float w3 = 0.5f * (t3 - t2);
        #pragma unroll
        for (int o = 0; o < 4; ++o) {
            int v = i0 - 1 + o;
            v = v < 0 ? 0 : (v > 127 ? 127 : v);
            if (d == 0) offa[o] = v * 65536;   // *128*128*4
            if (d == 1) offb[o] = v * 512;     // *128*4
            if (d == 2) offc[o] = v * 4;       // *4
        }
        float* wp = (d == 0) ? wx : (d == 1) ? wy : wz;
        wp[0] = w0; wp[1] = w1v; wp[2] = w2v; wp[3] = w3;
    }

    // ---- tricubic gather: 64 cells x 16 feats ----
    // One z-row (4 cells = 16 float4) in flight at a time; memory-level
    // parallelism comes from occupancy, not per-thread unroll. Keeps VGPR<=128.
    float4 acc0 = make_float4(0.f, 0.f, 0.f, 0.f);
    float4 acc1 = acc0, acc2 = acc0, acc3 = acc0;
    const float4* __restrict__ g4 = (const float4*)grid;

    #pragma unroll 1
    for (int a = 0; a < 4; ++a) {
        const float wa = wx[a];
        #pragma unroll 1
        for (int b = 0; b < 4; ++b) {
            const float wab = wa * wy[b];
            const int   rb  = offa[a] + offb[b];
            #pragma unroll
            for (int c = 0; c < 4; ++c) {
                const float w = wab * wz[c];
                const float4* cell = g4 + (rb + offc[c]);
                fma4(acc0, w, cell[0]);
                fma4(acc1, w, cell[1]);
                fma4(acc2, w, cell[2]);
                fma4(acc3, w, cell[3]);
            }
        }
    }

    // ---- assemble MLP input: 16 feats + 9 positional sins ----
    float h[IN_MLP];
    h[0]  = acc0.x; h[1]  = acc0.y; h[2]  = acc0.z; h[3]  = acc0.w;
    h[4]  = acc1.x; h[5]  = acc1.y; h[6]  = acc1.z; h[7]  = acc1.w;
    h[8]  = acc2.x; h[9]  = acc2.y; h[10] = acc2.z; h[11] = acc2.w;
    h[12] = acc3.x; h[13] = acc3.y; h[14] = acc3.z; h[15] = acc3.w;

    // sin(2*pi*k*t) == v_sin_f32(k*t): gfx950 v_sin takes REVOLUTIONS,
    // so the 2*pi multiply and libm range reduction vanish entirely.
    #pragma unroll
    for (int k = 0; k < 3; ++k) {
        #pragma unroll
        for (int d = 0; d < 3; ++d) {
            h[16 + k * 3 + d] = __builtin_amdgcn_sinf((float)(k + 1) * t[d]);
        }
    }

    // ---- MLP: 25 -> 64 (swish) -> 1 ----
    // Weight reads are wave-uniform -> scalar s_load path.
    float o = b2[0];
    #pragma unroll 4
    for (int j = 0; j < WIDTH; ++j) {
        float hj = b1[j];
        #pragma unroll
        for (int k = 0; k < IN_MLP; ++k) {
            hj = fmaf(h[k], w1[j * IN_MLP + k], hj);
        }
        const float sig = 1.0f / (1.0f + __expf(-hj));
        o = fmaf(hj * sig, w2[j], o);
    }
    out[p] = o;
}

extern "C" void kernel_launch(void* const* d_in, const int* in_sizes, int n_in,
                              void* d_out, int out_size, void* d_ws, size_t ws_size,
                              hipStream_t stream) {
    const float* x    = (const float*)d_in[0];
    const float* grid = (const float*)d_in[1];
    const float* w1   = (const float*)d_in[2];
    const float* b1   = (const float*)d_in[3];
    const float* w2   = (const float*)d_in[4];
    const float* b2   = (const float*)d_in[5];
    float* out = (float*)d_out;

    const int threads = 256;
    const int blocks  = (NPTS + threads - 1) / threads;
    gridnet_kernel<<<blocks, threads, 0, stream>>>(x, grid, w1, b1, w2, b2, out);
}

// Round 8
// 566.046 us; speedup vs baseline: 1.5416x; 1.2189x over previous
//
#include <hip/hip_runtime.h>
#include <cmath>

#define NGRID 128
#define FEAT 16
#define WIDTH 64
#define NPTS 262144
#define IN_MLP 25
#define NB 16            // coarse buckets per dim (8^3 cells each)
#define NBUCKETS 4096    // 16^3

// ws layout: [0, 16384): bucket counters/offsets (4096 int)
//            [16384, 16384+NPTS*4): permutation (point ids in bucket order)
#define WS_NEEDED (NBUCKETS * 4 + NPTS * 4)

__device__ __forceinline__ int bucket_of(const float* __restrict__ x, int p) {
    int key = 0;
    #pragma unroll
    for (int d = 0; d < 3; ++d) {
        int i0 = (int)floorf(x[3 * p + d] * 127.0f);
        i0 = i0 < 0 ? 0 : (i0 > 126 ? 126 : i0);
        key = (key << 4) | (i0 >> 3);
    }
    return key;
}

__global__ void zero_hist_kernel(int* __restrict__ hist) {
    hist[blockIdx.x * 256 + threadIdx.x] = 0;
}

__global__ void hist_kernel(const float* __restrict__ x, int* __restrict__ hist) {
    const int p = blockIdx.x * blockDim.x + threadIdx.x;
    if (p >= NPTS) return;
    atomicAdd(&hist[bucket_of(x, p)], 1);
}

// Exclusive scan of 4096 ints, single block of 1024 threads.
__global__ __launch_bounds__(1024) void scan_kernel(int* __restrict__ hist) {
    __shared__ int lds[1024];
    const int t = threadIdx.x;
    int4 v = ((int4*)hist)[t];
    lds[t] = v.x + v.y + v.z + v.w;
    __syncthreads();
    #pragma unroll
    for (int off = 1; off < 1024; off <<= 1) {
        int val = lds[t];
        int add = (t >= off) ? lds[t - off] : 0;
        __syncthreads();
        lds[t] = val + add;
        __syncthreads();
    }
    const int excl = (t == 0) ? 0 : lds[t - 1];
    int4 o;
    o.x = excl;
    o.y = excl + v.x;
    o.z = excl + v.x + v.y;
    o.w = excl + v.x + v.y + v.z;
    ((int4*)hist)[t] = o;
}

__global__ void scatter_kernel(const float* __restrict__ x, int* __restrict__ offs,
                               int* __restrict__ perm) {
    const int p = blockIdx.x * blockDim.x + threadIdx.x;
    if (p >= NPTS) return;
    const int pos = atomicAdd(&offs[bucket_of(x, p)], 1);
    perm[pos] = p;
}

__device__ __forceinline__ void fma4(float4& a, float w, const float4 c) {
    a.x = fmaf(w, c.x, a.x);
    a.y = fmaf(w, c.y, a.y);
    a.z = fmaf(w, c.z, a.z);
    a.w = fmaf(w, c.w, a.w);
}

template <bool SORTED>
__global__ __launch_bounds__(128, 8) void gridnet_kernel(
    const float* __restrict__ x,
    const float* __restrict__ grid,
    const float* __restrict__ w1,
    const float* __restrict__ b1,
    const float* __restrict__ w2,
    const float* __restrict__ b2,
    const int* __restrict__ perm,
    float* __restrict__ out)
{
    // XCD-chunked swizzle: 2048 blocks, 8 XCDs -> XCD k processes a contiguous
    // sorted-point range (contiguous spatial slab) for private-L2 locality.
    const int bid = blockIdx.x;
    const int swz = SORTED ? ((bid & 7) * 256 + (bid >> 3)) : bid;
    const int gid = swz * 128 + threadIdx.x;
    const int p = SORTED ? perm[gid] : gid;

    // ---- per-dimension index + cubic weight setup ----
    int   offa[4], offb[4], offc[4];
    float wx[4], wy[4], wz[4];
    float t[3];
    #pragma unroll
    for (int d = 0; d < 3; ++d) {
        const float u  = x[3 * p + d] * 127.0f;   // x * (n - 1)
        const float fu = floorf(u);
        const float td = u - fu;
        t[d] = td;
        const int i0 = (int)fu;
        const float t2 = td * td;
        const float t3 = t2 * td;
        float w0 = 0.5f * (-t3 + 2.0f * t2 - td);
        float w1v = 0.5f * (3.0f * t3 - 5.0f * t2 + 2.0f);
        float w2v = 0.5f * (-3.0f * t3 + 4.0f * t2 + td);
        float w3 = 0.5f * (t3 - t2);
        #pragma unroll
        for (int o = 0; o < 4; ++o) {
            int v = i0 - 1 + o;
            v = v < 0 ? 0 : (v > 127 ? 127 : v);
            if (d == 0) offa[o] = v * 65536;   // *128*128*4 (float4 units)
            if (d == 1) offb[o] = v * 512;     // *128*4
            if (d == 2) offc[o] = v * 4;       // *4
        }
        float* wp = (d == 0) ? wx : (d == 1) ? wy : wz;
        wp[0] = w0; wp[1] = w1v; wp[2] = w2v; wp[3] = w3;
    }

    // ---- tricubic gather: 64 cells x 16 feats, one z-row in flight ----
    float4 acc0 = make_float4(0.f, 0.f, 0.f, 0.f);
    float4 acc1 = acc0, acc2 = acc0, acc3 = acc0;
    const float4* __restrict__ g4 = (const float4*)grid;

    #pragma unroll 1
    for (int a = 0; a < 4; ++a) {
        const float wa = wx[a];
        #pragma unroll 1
        for (int b = 0; b < 4; ++b) {
            const float wab = wa * wy[b];
            const int   rb  = offa[a] + offb[b];
            #pragma unroll
            for (int c = 0; c < 4; ++c) {
                const float w = wab * wz[c];
                const float4* cell = g4 + (rb + offc[c]);
                fma4(acc0, w, cell[0]);
                fma4(acc1, w, cell[1]);
                fma4(acc2, w, cell[2]);
                fma4(acc3, w, cell[3]);
            }
        }
    }

    // ---- assemble MLP input: 16 feats + 9 positional sins ----
    float h[IN_MLP];
    h[0]  = acc0.x; h[1]  = acc0.y; h[2]  = acc0.z; h[3]  = acc0.w;
    h[4]  = acc1.x; h[5]  = acc1.y; h[6]  = acc1.z; h[7]  = acc1.w;
    h[8]  = acc2.x; h[9]  = acc2.y; h[10] = acc2.z; h[11] = acc2.w;
    h[12] = acc3.x; h[13] = acc3.y; h[14] = acc3.z; h[15] = acc3.w;

    // sin(2*pi*k*t) == v_sin_f32(k*t): gfx950 v_sin takes REVOLUTIONS.
    #pragma unroll
    for (int k = 0; k < 3; ++k) {
        #pragma unroll
        for (int d = 0; d < 3; ++d) {
            h[16 + k * 3 + d] = __builtin_amdgcn_sinf((float)(k + 1) * t[d]);
        }
    }

    // ---- MLP: 25 -> 64 (swish) -> 1 (wave-uniform weight reads -> s_load) ----
    float o = b2[0];
    #pragma unroll 4
    for (int j = 0; j < WIDTH; ++j) {
        float hj = b1[j];
        #pragma unroll
        for (int k = 0; k < IN_MLP; ++k) {
            hj = fmaf(h[k], w1[j * IN_MLP + k], hj);
        }
        const float sig = 1.0f / (1.0f + __expf(-hj));
        o = fmaf(hj * sig, w2[j], o);
    }
    out[p] = o;
}

extern "C" void kernel_launch(void* const* d_in, const int* in_sizes, int n_in,
                              void* d_out, int out_size, void* d_ws, size_t ws_size,
                              hipStream_t stream) {
    const float* x    = (const float*)d_in[0];
    const float* grid = (const float*)d_in[1];
    const float* w1   = (const float*)d_in[2];
    const float* b1   = (const float*)d_in[3];
    const float* w2   = (const float*)d_in[4];
    const float* b2   = (const float*)d_in[5];
    float* out = (float*)d_out;

    if (ws_size >= (size_t)WS_NEEDED) {
        int* hist = (int*)d_ws;
        int* perm = (int*)((char*)d_ws + NBUCKETS * 4);
        zero_hist_kernel<<<NBUCKETS / 256, 256, 0, stream>>>(hist);
        hist_kernel<<<NPTS / 256, 256, 0, stream>>>(x, hist);
        scan_kernel<<<1, 1024, 0, stream>>>(hist);
        scatter_kernel<<<NPTS / 256, 256, 0, stream>>>(x, hist, perm);
        gridnet_kernel<true><<<NPTS / 128, 128, 0, stream>>>(
            x, grid, w1, b1, w2, b2, perm, out);
    } else {
        gridnet_kernel<false><<<NPTS / 128, 128, 0, stream>>>(
            x, grid, w1, b1, w2, b2, nullptr, out);
    }
}